// Round 7
// baseline (344.877 us; speedup 1.0000x reference)
//
#include <hip/hip_runtime.h>
#include <hip/hip_cooperative_groups.h>
#include <hip/hip_bf16.h>

namespace cg = cooperative_groups;

#define T_DIM 6
#define N_NODES 10000
#define TOTAL_ROWS (T_DIM * N_NODES)   // 60000
#define LOG2E 1.44269504088896340736f
#define QPRE (0.25f * LOG2E)           // dh^-0.5 * log2(e): softmax done in exp2 domain
#define EPS_GATE 1e-6f
#define NEGBIG (-1e30f)
#define NCHUNK 40                      // ceil(10000/256)

typedef unsigned int u32;
typedef unsigned short u16;
typedef __attribute__((ext_vector_type(8))) short bf16x8;
typedef __attribute__((ext_vector_type(4))) float f32x4;

#define MFMA16(a, b, c) __builtin_amdgcn_mfma_f32_16x16x32_bf16(a, b, c, 0, 0, 0)

__device__ __forceinline__ float fast_exp2(float x) {
#if __has_builtin(__builtin_amdgcn_exp2f)
    return __builtin_amdgcn_exp2f(x);
#else
    return exp2f(x);
#endif
}

// DPP butterfly add within 8-lane groups.
template <int CTRL>
__device__ __forceinline__ float dpp_add(float x) {
    int v = __builtin_amdgcn_update_dpp(0, __float_as_int(x), CTRL, 0xf, 0xf, true);
    return x + __int_as_float(v);
}
__device__ __forceinline__ float red8(float x) {
    x = dpp_add<0xB1>(x);   // quad_perm {1,0,3,2} : lane ^ 1
    x = dpp_add<0x4E>(x);   // quad_perm {2,3,0,1} : lane ^ 2
    x = dpp_add<0x141>(x);  // row_half_mirror     : l -> 7-l within 8
    return x;
}

__device__ __forceinline__ float bf2f(u16 u) {
    union { unsigned int i; float f; } c;
    c.i = ((unsigned int)u) << 16;
    return c.f;
}

__device__ __forceinline__ u16 f2bf(float f) {
    union { float f; unsigned int i; } c; c.f = f;
    unsigned int i = c.i;
    unsigned int lsb = (i >> 16) & 1u;
    i += 0x7FFFu + lsb;          // round-to-nearest-even (finite data only)
    return (u16)(i >> 16);
}

// ============ ONE cooperative kernel: prep | hist+proj | scan | scatter | agg ============
__global__ __launch_bounds__(256, 4) void mega_kernel(
    const float* __restrict__ H,
    const float* __restrict__ S,
    const float* __restrict__ Wq, const float* __restrict__ Wk, const float* __restrict__ Wv,
    const int* __restrict__ esrc, const int* __restrict__ edst, int E,
    int* __restrict__ counts, int* __restrict__ rank_, int* __restrict__ row_ptr,
    int* __restrict__ edge_list, int* __restrict__ bsum,
    u16* __restrict__ whi_g, u16* __restrict__ wlo_g,
    float* __restrict__ gate, float* __restrict__ kpe, float* __restrict__ bias,
    u16* __restrict__ Kb, u16* __restrict__ Vb,
    float* out)                                  // also holds Q (prescaled), layout [t][n][64]
{
    cg::grid_group grid = cg::this_grid();
    __shared__ int sd[256];
    __shared__ int cpre[NCHUNK + 1];

    const int tid = threadIdx.x;
    const int gtid = blockIdx.x * 256 + tid;
    const int gsz = gridDim.x * 256;

    // ---------------- P0: zero counts, gate table, kpe/bias, W hi/lo split ----------------
    for (int i = gtid; i < N_NODES; i += gsz) counts[i] = 0;
    for (int i = gtid; i < TOTAL_ROWS; i += gsz) {
        int t = i / N_NODES, n = i - t * N_NODES;
        gate[n * T_DIM + t] = log2f(S[i] + EPS_GATE);
    }
    for (int i = gtid; i < 192 * 64; i += gsz) {   // cols 0-63 Q, 64-127 K, 128-191 V
        int col = i >> 6, k = i & 63;
        float w;
        if (col < 64)       w = Wq[col * 64 + k];
        else if (col < 128) w = Wk[(col - 64) * 72 + k];
        else                w = Wv[(col - 128) * 64 + k];
        u16 hb = f2bf(w);
        whi_g[i] = hb;
        wlo_g[i] = f2bf(w - bf2f(hb));
    }
    if (blockIdx.x == 0 && tid < 64) {
        int c = tid;
        for (int dt = 0; dt < 9; ++dt) {
            float fdt = (float)dt;
            float pe[8];
            pe[0] = expf(-fdt * 0.25f);
            pe[1] = expf(-fdt * 0.0625f);
            pe[2] = sinf(fdt * 1.0f);
            pe[3] = sinf(fdt * 0.5f);
            pe[4] = sinf(fdt * 0.25f);
            pe[5] = cosf(fdt * 1.0f);
            pe[6] = cosf(fdt * 0.5f);
            pe[7] = cosf(fdt * 0.25f);
            float acc = 0.f;
            #pragma unroll
            for (int j = 0; j < 8; ++j) acc += pe[j] * Wk[c * 72 + 64 + j];
            kpe[dt * 64 + c] = acc;
            if (c == 0) bias[dt] = -log2f(1.0f + fdt);
        }
    }
    grid.sync();   // S1

    // ---------------- P1: histogram+rank, then MFMA projection ----------------
    for (int e = gtid; e < E; e += gsz) rank_[e] = atomicAdd(&counts[edst[e]], 1);

    {
        const int lane = tid & 63;
        const int mrow = lane & 15;
        const int kgrp = lane >> 4;                 // 0..3
        const int wv = blockIdx.x * 4 + (tid >> 6);
        const int nw = gridDim.x * 4;
        for (int rt = wv; rt < TOTAL_ROWS / 32; rt += nw) {   // 1875 tiles of 32 rows
            int r0 = rt * 32;
            // A fragments: [mtile][kstep], hi+lo split
            bf16x8 ahi[2][2], alo[2][2];
            #pragma unroll
            for (int mt = 0; mt < 2; ++mt) {
                #pragma unroll
                for (int ks = 0; ks < 2; ++ks) {
                    const float* hp = H + (size_t)(r0 + mt * 16 + mrow) * 64 + ks * 32 + kgrp * 8;
                    float4 hA = *(const float4*)hp;
                    float4 hB = *(const float4*)(hp + 4);
                    float tmp[8] = {hA.x, hA.y, hA.z, hA.w, hB.x, hB.y, hB.z, hB.w};
                    #pragma unroll
                    for (int b = 0; b < 8; ++b) {
                        u16 hb = f2bf(tmp[b]);
                        ahi[mt][ks][b] = (short)hb;
                        alo[mt][ks][b] = (short)f2bf(tmp[b] - bf2f(hb));
                    }
                }
            }
            #pragma unroll
            for (int nt = 0; nt < 12; ++nt) {
                f32x4 acc0 = {0.f, 0.f, 0.f, 0.f};
                f32x4 acc1 = {0.f, 0.f, 0.f, 0.f};
                #pragma unroll
                for (int ks = 0; ks < 2; ++ks) {
                    int wo = (nt * 16 + mrow) * 64 + ks * 32 + kgrp * 8;
                    bf16x8 bh = *(const bf16x8*)&whi_g[wo];
                    bf16x8 bl = *(const bf16x8*)&wlo_g[wo];
                    acc0 = MFMA16(ahi[0][ks], bh, acc0);
                    acc0 = MFMA16(ahi[0][ks], bl, acc0);
                    acc0 = MFMA16(alo[0][ks], bh, acc0);
                    acc1 = MFMA16(ahi[1][ks], bh, acc1);
                    acc1 = MFMA16(ahi[1][ks], bl, acc1);
                    acc1 = MFMA16(alo[1][ks], bh, acc1);
                }
                // C col = lane&15, row = (lane>>4)*4 + j   [m89-verified]
                #pragma unroll
                for (int mt = 0; mt < 2; ++mt) {
                    f32x4 acc = mt ? acc1 : acc0;
                    int mbase = r0 + mt * 16 + kgrp * 4;
                    #pragma unroll
                    for (int j = 0; j < 4; ++j) {
                        int gr = mbase + j;
                        float v = acc[j];
                        if (nt < 4) {
                            out[(size_t)gr * 64 + nt * 16 + mrow] = v * QPRE;
                        } else if (nt < 8) {
                            int t = gr / N_NODES, n = gr - t * N_NODES;
                            Kb[((size_t)n * T_DIM + t) * 64 + (nt - 4) * 16 + mrow] = f2bf(v);
                        } else {
                            int t = gr / N_NODES, n = gr - t * N_NODES;
                            Vb[((size_t)n * T_DIM + t) * 64 + (nt - 8) * 16 + mrow] = f2bf(v);
                        }
                    }
                }
            }
        }
    }
    grid.sync();   // S2

    // ---------------- P2a: per-chunk exclusive scan (Hillis-Steele in LDS) ----------------
    for (int c = blockIdx.x; c < NCHUNK; c += gridDim.x) {
        int i = c * 256 + tid;
        int v = (i < N_NODES) ? counts[i] : 0;
        sd[tid] = v;
        __syncthreads();
        int incl = v;
        #pragma unroll
        for (int off = 1; off < 256; off <<= 1) {
            int a = (tid >= off) ? sd[tid - off] : 0;
            __syncthreads();
            incl += a;
            sd[tid] = incl;
            __syncthreads();
        }
        if (i < N_NODES) row_ptr[i] = incl - v;    // chunk-local exclusive prefix
        if (tid == 255) bsum[c] = incl;            // chunk total
        __syncthreads();
    }
    grid.sync();   // S3

    // ---------------- P2b: chunk-prefix combine -> final row_ptr ----------------
    if (tid == 0) {
        int s = 0;
        for (int j = 0; j < NCHUNK; ++j) { cpre[j] = s; s += bsum[j]; }
        cpre[NCHUNK] = s;
    }
    __syncthreads();
    for (int c = blockIdx.x; c < NCHUNK; c += gridDim.x) {
        int i = c * 256 + tid;
        if (i < N_NODES) row_ptr[i] += cpre[c];
    }
    if (gtid == 0) row_ptr[N_NODES] = cpre[NCHUNK];
    grid.sync();   // S4

    // ---------------- P3: atomic-free scatter via rank ----------------
    for (int e = gtid; e < E; e += gsz)
        edge_list[row_ptr[edst[e]] + rank_[e]] = esrc[e];
    grid.sync();   // S5

    // ---------------- P4: aggregation, 2 edges/iteration, grid-stride over nodes ----------------
    {
        const int lane = tid & 63;
        const int half = lane >> 5;
        const int l32 = lane & 31;
        const int doff = ((l32 >> 3) << 4) + ((l32 & 7) << 1);   // h*16 + 2*p
        const int wv = blockIdx.x * 4 + (tid >> 6);
        const int nw = gridDim.x * 4;
        const float* Qs = out;

        for (int n = wv; n < N_NODES; n += nw) {
            int e0 = row_ptr[n], e1 = row_ptr[n + 1];
            if (e0 >= e1) {                        // zero-degree: output 0 (matches ref clip)
                if (half == 0) {
                    #pragma unroll
                    for (int t = 0; t < T_DIM; ++t)
                        *(float2*)(out + ((size_t)t * N_NODES + n) * 64 + doff) = make_float2(0.f, 0.f);
                }
                continue;
            }

            float q0[T_DIM], q1[T_DIM];
            #pragma unroll
            for (int t = 0; t < T_DIM; ++t) {
                float2 qq = *(const float2*)(Qs + ((size_t)t * N_NODES + n) * 64 + doff);
                q0[t] = qq.x; q1[t] = qq.y;
            }

            // cc[tri(t,dt)] = dot16(q[t], K_pe[dt]) + bias[dt]
            float cc[21];
            #pragma unroll
            for (int dt = 0; dt < T_DIM; ++dt) {
                float2 kp = *(const float2*)(kpe + dt * 64 + doff);
                float b = bias[dt];
                #pragma unroll
                for (int t = dt; t < T_DIM; ++t)
                    cc[t * (t + 1) / 2 + dt] = red8(fmaf(q1[t], kp.y, q0[t] * kp.x)) + b;
            }

            float den[T_DIM] = {0,0,0,0,0,0};
            float nu0[T_DIM] = {0,0,0,0,0,0};
            float nu1[T_DIM] = {0,0,0,0,0,0};

            int npairs = (e1 - e0 + 1) >> 1;
            u32 ku[T_DIM], vu[T_DIM];
            float gg[T_DIM];

            {   // prologue: pair 0 (odd tail padded via g = -1e30 -> weight 0)
                int i = e0 + half;
                int s = edge_list[min(i, e1 - 1)];
                const u16* kb = Kb + (size_t)s * (T_DIM * 64) + doff;
                const u16* vb = Vb + (size_t)s * (T_DIM * 64) + doff;
                #pragma unroll
                for (int t = 0; t < T_DIM; ++t) {
                    ku[t] = *(const u32*)(kb + t * 64);
                    vu[t] = *(const u32*)(vb + t * 64);
                }
                bool val = i < e1;
                const float* gp = gate + (size_t)s * T_DIM;
                float2 g01 = *(const float2*)(gp);
                float2 g23 = *(const float2*)(gp + 2);
                float2 g45 = *(const float2*)(gp + 4);
                gg[0] = val ? g01.x : NEGBIG; gg[1] = val ? g01.y : NEGBIG;
                gg[2] = val ? g23.x : NEGBIG; gg[3] = val ? g23.y : NEGBIG;
                gg[4] = val ? g45.x : NEGBIG; gg[5] = val ? g45.y : NEGBIG;
            }

            for (int p = 0; p < npairs; ++p) {
                // prefetch next pair (clamped; overlaps compute)
                u32 ku2[T_DIM], vu2[T_DIM];
                float gg2[T_DIM];
                {
                    int i = e0 + (p + 1) * 2 + half;
                    int s = edge_list[min(i, e1 - 1)];
                    const u16* kb = Kb + (size_t)s * (T_DIM * 64) + doff;
                    const u16* vb = Vb + (size_t)s * (T_DIM * 64) + doff;
                    #pragma unroll
                    for (int t = 0; t < T_DIM; ++t) {
                        ku2[t] = *(const u32*)(kb + t * 64);
                        vu2[t] = *(const u32*)(vb + t * 64);
                    }
                    bool val = i < e1;
                    const float* gp = gate + (size_t)s * T_DIM;
                    float2 g01 = *(const float2*)(gp);
                    float2 g23 = *(const float2*)(gp + 2);
                    float2 g45 = *(const float2*)(gp + 4);
                    gg2[0] = val ? g01.x : NEGBIG; gg2[1] = val ? g01.y : NEGBIG;
                    gg2[2] = val ? g23.x : NEGBIG; gg2[3] = val ? g23.y : NEGBIG;
                    gg2[4] = val ? g45.x : NEGBIG; gg2[5] = val ? g45.y : NEGBIG;
                }
                // compute current pair
                float k0[T_DIM], k1[T_DIM], v0[T_DIM], v1[T_DIM];
                #pragma unroll
                for (int t = 0; t < T_DIM; ++t) {
                    k0[t] = __int_as_float((int)(ku[t] << 16));
                    k1[t] = __int_as_float((int)(ku[t] & 0xffff0000u));
                    v0[t] = __int_as_float((int)(vu[t] << 16));
                    v1[t] = __int_as_float((int)(vu[t] & 0xffff0000u));
                }
                #pragma unroll
                for (int t = 0; t < T_DIM; ++t) {
                    #pragma unroll
                    for (int dt = 0; dt <= t; ++dt) {
                        int tp = t - dt;
                        float d = red8(fmaf(q1[t], k1[tp], q0[t] * k0[tp]));
                        float wt = fast_exp2(d + cc[t * (t + 1) / 2 + dt] + gg[tp]);
                        den[t] += wt;
                        nu0[t] = fmaf(wt, v0[tp], nu0[t]);
                        nu1[t] = fmaf(wt, v1[tp], nu1[t]);
                    }
                }
                #pragma unroll
                for (int t = 0; t < T_DIM; ++t) { ku[t] = ku2[t]; vu[t] = vu2[t]; gg[t] = gg2[t]; }
            }

            #pragma unroll
            for (int t = 0; t < T_DIM; ++t) {
                den[t] += __shfl_xor(den[t], 32);
                nu0[t] += __shfl_xor(nu0[t], 32);
                nu1[t] += __shfl_xor(nu1[t], 32);
            }
            if (half == 0) {
                #pragma unroll
                for (int t = 0; t < T_DIM; ++t) {
                    float r = 1.0f / fmaxf(den[t], 1e-12f);
                    *(float2*)(out + ((size_t)t * N_NODES + n) * 64 + doff) =
                        make_float2(nu0[t] * r, nu1[t] * r);
                }
            }
        }
    }
}

extern "C" void kernel_launch(void* const* d_in, const int* in_sizes, int n_in,
                              void* d_out, int out_size, void* d_ws, size_t ws_size,
                              hipStream_t stream) {
    const float* H  = (const float*)d_in[0];
    const float* S  = (const float*)d_in[1];
    const float* Wq = (const float*)d_in[2];
    const float* Wk = (const float*)d_in[3];
    const float* Wv = (const float*)d_in[4];
    const int* edge = (const int*)d_in[5];
    int E = in_sizes[5] / 2;
    const int* esrc = edge;
    const int* edst = edge + E;
    float* out = (float*)d_out;

    char* ws = (char*)d_ws;
    size_t off = 0;
    auto alloc = [&](size_t b) { char* p = ws + off; off += (b + 255) & ~(size_t)255; return (void*)p; };
    u16*   Kb        = (u16*)  alloc((size_t)TOTAL_ROWS * 64 * 2);   // 7.68 MB
    u16*   Vb        = (u16*)  alloc((size_t)TOTAL_ROWS * 64 * 2);   // 7.68 MB
    float* gate      = (float*)alloc((size_t)TOTAL_ROWS * 4);        // 240 KB
    float* kpe       = (float*)alloc(9 * 64 * 4);
    float* bias      = (float*)alloc(9 * 4);
    int*   counts    = (int*)  alloc((size_t)N_NODES * 4);
    int*   rank_arr  = (int*)  alloc((size_t)E * 4);
    int*   row_ptr   = (int*)  alloc((size_t)(N_NODES + 1) * 4);
    int*   edge_list = (int*)  alloc((size_t)E * 4);
    int*   bsum      = (int*)  alloc(NCHUNK * 4);
    u16*   whi_g     = (u16*)  alloc(192 * 64 * 2);
    u16*   wlo_g     = (u16*)  alloc(192 * 64 * 2);

    int nbpc = 0;
    if (hipOccupancyMaxActiveBlocksPerMultiprocessor(&nbpc, mega_kernel, 256, 0) != hipSuccess || nbpc < 1)
        nbpc = 2;
    int grid = nbpc * 256;                 // 256 CUs on MI355X; cooperative residency guaranteed
    if (grid > 2048) grid = 2048;

    void* args[] = {
        (void*)&H, (void*)&S, (void*)&Wq, (void*)&Wk, (void*)&Wv,
        (void*)&esrc, (void*)&edst, (void*)&E,
        (void*)&counts, (void*)&rank_arr, (void*)&row_ptr,
        (void*)&edge_list, (void*)&bsum,
        (void*)&whi_g, (void*)&wlo_g,
        (void*)&gate, (void*)&kpe, (void*)&bias,
        (void*)&Kb, (void*)&Vb, (void*)&out
    };
    hipLaunchCooperativeKernel(mega_kernel, dim3(grid), dim3(256), args, 0, stream);
}

// Round 8
// 259.393 us; speedup vs baseline: 1.3296x; 1.3296x over previous
//
#include <hip/hip_runtime.h>
#include <hip/hip_bf16.h>

#define T_DIM 6
#define N_NODES 10000
#define TOTAL_ROWS (T_DIM * N_NODES)   // 60000
#define LOG2E 1.44269504088896340736f
#define QPRE (0.25f * LOG2E)           // dh^-0.5 * log2(e): softmax done in exp2 domain
#define EPS_GATE 1e-6f

typedef unsigned int u32;
typedef unsigned short u16;
typedef __attribute__((ext_vector_type(8))) short bf16x8;
typedef __attribute__((ext_vector_type(4))) float f32x4;

#define MFMA16(a, b, c) __builtin_amdgcn_mfma_f32_16x16x32_bf16(a, b, c, 0, 0, 0)

__device__ __forceinline__ float fast_exp2(float x) {
#if __has_builtin(__builtin_amdgcn_exp2f)
    return __builtin_amdgcn_exp2f(x);
#else
    return exp2f(x);
#endif
}

// DPP butterfly add within 8-lane groups.
template <int CTRL>
__device__ __forceinline__ float dpp_add(float x) {
    int v = __builtin_amdgcn_update_dpp(0, __float_as_int(x), CTRL, 0xf, 0xf, true);
    return x + __int_as_float(v);
}
__device__ __forceinline__ float red8(float x) {
    x = dpp_add<0xB1>(x);   // quad_perm {1,0,3,2} : lane ^ 1
    x = dpp_add<0x4E>(x);   // quad_perm {2,3,0,1} : lane ^ 2
    x = dpp_add<0x141>(x);  // row_half_mirror     : l -> 7-l within 8
    return x;
}

__device__ __forceinline__ float bf2f(u16 u) {
    union { unsigned int i; float f; } c;
    c.i = ((unsigned int)u) << 16;
    return c.f;
}

__device__ __forceinline__ u16 f2bf(float f) {
    union { float f; unsigned int i; } c; c.f = f;
    unsigned int i = c.i;
    unsigned int lsb = (i >> 16) & 1u;
    i += 0x7FFFu + lsb;          // round-to-nearest-even (finite data only)
    return (u16)(i >> 16);
}

// ---------------- zero counts/nu/den + kpe/bias tables ----------------
__global__ void zero_kernel(int* __restrict__ counts,
                            float* __restrict__ nu, float* __restrict__ den,
                            const float* __restrict__ Wk,
                            float* __restrict__ kpe, float* __restrict__ bias) {
    int gtid = blockIdx.x * blockDim.x + threadIdx.x;
    int gsz = gridDim.x * blockDim.x;
    float4 z4 = make_float4(0.f, 0.f, 0.f, 0.f);
    for (int i = gtid; i < N_NODES; i += gsz) counts[i] = 0;
    for (int i = gtid; i < TOTAL_ROWS * 16; i += gsz) ((float4*)nu)[i] = z4;   // 15.36 MB
    for (int i = gtid; i < TOTAL_ROWS; i += gsz) ((float4*)den)[i] = z4;       // 0.96 MB
    if (blockIdx.x == 0 && threadIdx.x < 64) {
        int c = threadIdx.x;
        for (int dt = 0; dt < 9; ++dt) {
            float fdt = (float)dt;
            float pe[8];
            pe[0] = expf(-fdt * 0.25f);    // tau=4
            pe[1] = expf(-fdt * 0.0625f);  // tau=16
            pe[2] = sinf(fdt * 1.0f);
            pe[3] = sinf(fdt * 0.5f);
            pe[4] = sinf(fdt * 0.25f);
            pe[5] = cosf(fdt * 1.0f);
            pe[6] = cosf(fdt * 0.5f);
            pe[7] = cosf(fdt * 0.25f);
            float acc = 0.f;
            #pragma unroll
            for (int j = 0; j < 8; ++j) acc += pe[j] * Wk[c * 72 + 64 + j];
            kpe[dt * 64 + c] = acc;
            if (c == 0) bias[dt] = -log2f(1.0f + fdt);
        }
    }
}

// ---------------- fused prep + source-degree hist + QKV projection (split-bf16 MFMA) ----------------
// Q (prescaled by QPRE), K, V all bf16, layout [n][t][64] (per-node 768B contiguous).
__global__ __launch_bounds__(256) void proj_kernel(
    const float* __restrict__ H,
    const float* __restrict__ S,
    const float* __restrict__ Wq, const float* __restrict__ Wk,
    const float* __restrict__ Wv,
    const int* __restrict__ esrc, int E, int* __restrict__ counts,
    u16* __restrict__ Qb, u16* __restrict__ Kb, u16* __restrict__ Vb,
    float* __restrict__ gate) {
    int tid = threadIdx.x;
    int gtid = blockIdx.x * 256 + tid;
    int gstride = gridDim.x * 256;
    // ---- fused prep ----
    if (gtid < TOTAL_ROWS) {
        int t = gtid / N_NODES, n = gtid - t * N_NODES;
        gate[n * T_DIM + t] = log2f(S[gtid] + EPS_GATE);
    }
    for (int e = gtid; e < E; e += gstride) atomicAdd(&counts[esrc[e]], 1);

    // ---- weight staging ----
    __shared__ short whi[192][72];   // stride 72 shorts = 144B -> 2-way banks (free)
    __shared__ short wlo[192][72];
    for (int i = tid; i < 192 * 64; i += 256) {
        int col = i >> 6, k = i & 63;
        float w;
        if (col < 64)       w = Wq[col * 64 + k];
        else if (col < 128) w = Wk[(col - 64) * 72 + k];   // first 64 input dims of W_k
        else                w = Wv[(col - 128) * 64 + k];
        u16 hb = f2bf(w);
        u16 lb = f2bf(w - bf2f(hb));
        whi[col][k] = (short)hb;
        wlo[col][k] = (short)lb;
    }
    __syncthreads();

    int lane = tid & 63, wid = tid >> 6;
    int r0 = (blockIdx.x * 4 + wid) * 32;          // 32 rows per wave (60000 = 32*1875)
    if (r0 >= TOTAL_ROWS) return;

    int mrow = lane & 15;
    int kgrp = lane >> 4;                          // 0..3

    // A fragments: [mtile][kstep], hi+lo split
    bf16x8 ahi[2][2], alo[2][2];
    #pragma unroll
    for (int mt = 0; mt < 2; ++mt) {
        #pragma unroll
        for (int ks = 0; ks < 2; ++ks) {
            const float* hp = H + (size_t)(r0 + mt * 16 + mrow) * 64 + ks * 32 + kgrp * 8;
            float4 hA = *(const float4*)hp;
            float4 hB = *(const float4*)(hp + 4);
            float tmp[8] = {hA.x, hA.y, hA.z, hA.w, hB.x, hB.y, hB.z, hB.w};
            #pragma unroll
            for (int b = 0; b < 8; ++b) {
                u16 hb = f2bf(tmp[b]);
                ahi[mt][ks][b] = (short)hb;
                alo[mt][ks][b] = (short)f2bf(tmp[b] - bf2f(hb));
            }
        }
    }

    #pragma unroll
    for (int nt = 0; nt < 12; ++nt) {
        f32x4 acc0 = {0.f, 0.f, 0.f, 0.f};
        f32x4 acc1 = {0.f, 0.f, 0.f, 0.f};
        #pragma unroll
        for (int ks = 0; ks < 2; ++ks) {
            bf16x8 bh = *(const bf16x8*)&whi[nt * 16 + mrow][ks * 32 + kgrp * 8];
            bf16x8 bl = *(const bf16x8*)&wlo[nt * 16 + mrow][ks * 32 + kgrp * 8];
            acc0 = MFMA16(ahi[0][ks], bh, acc0);
            acc0 = MFMA16(ahi[0][ks], bl, acc0);
            acc0 = MFMA16(alo[0][ks], bh, acc0);
            acc1 = MFMA16(ahi[1][ks], bh, acc1);
            acc1 = MFMA16(ahi[1][ks], bl, acc1);
            acc1 = MFMA16(alo[1][ks], bh, acc1);
        }
        // epilogue: C col = lane&15, row = (lane>>4)*4 + j   [m89-verified]
        #pragma unroll
        for (int mt = 0; mt < 2; ++mt) {
            f32x4 acc = mt ? acc1 : acc0;
            int mbase = r0 + mt * 16 + kgrp * 4;
            #pragma unroll
            for (int j = 0; j < 4; ++j) {
                int gr = mbase + j;
                float v = acc[j];
                int t = gr / N_NODES, n = gr - t * N_NODES;
                size_t o = ((size_t)n * T_DIM + t) * 64 + (nt & 3) * 16 + mrow;
                if (nt < 4)      Qb[o] = f2bf(v * QPRE);
                else if (nt < 8) Kb[o] = f2bf(v);
                else             Vb[o] = f2bf(v);
            }
        }
    }
}

// ---------------- single-block exclusive scan over 10K counts -> CSR row_ptr ----------------
#define SCAN_THREADS 1024
#define SCAN_CHUNK 10            // 1024*10 >= 10000
__global__ __launch_bounds__(SCAN_THREADS) void scan_kernel(
    const int* __restrict__ counts,
    int* __restrict__ row_ptr,   // N+1
    int* __restrict__ cursor) {
    __shared__ int sums[SCAN_THREADS];
    int tid = threadIdx.x;
    int start = tid * SCAN_CHUNK;
    int local[SCAN_CHUNK];
    int s = 0;
    #pragma unroll
    for (int j = 0; j < SCAN_CHUNK; ++j) {
        int idx = start + j;
        int v = (idx < N_NODES) ? counts[idx] : 0;
        local[j] = s; s += v;
    }
    sums[tid] = s;
    __syncthreads();
    for (int off = 1; off < SCAN_THREADS; off <<= 1) {
        int v = sums[tid];
        int o = (tid >= off) ? sums[tid - off] : 0;
        __syncthreads();
        sums[tid] = v + o;
        __syncthreads();
    }
    int base = (tid > 0) ? sums[tid - 1] : 0;
    #pragma unroll
    for (int j = 0; j < SCAN_CHUNK; ++j) {
        int idx = start + j;
        if (idx < N_NODES) {
            int val = base + local[j];
            row_ptr[idx] = val;
            cursor[idx] = val;
        }
    }
    if (tid == SCAN_THREADS - 1) row_ptr[N_NODES] = sums[SCAN_THREADS - 1];
}

// ---------------- scatter: per-source edge lists storing DESTINATIONS ----------------
__global__ void scatter_kernel(const int* __restrict__ esrc, const int* __restrict__ edst,
                               int* __restrict__ cursor, int* __restrict__ edge_list, int E) {
    int e = blockIdx.x * blockDim.x + threadIdx.x;
    if (e < E) {
        int pos = atomicAdd(&cursor[esrc[e]], 1);
        edge_list[pos] = edst[e];
    }
}

// ---------------- aggregation: source-major, 2 edges/iter, atomic scatter to (nu, den) ----------------
// lanes: [half(2 edges)][head(4)][pair(8)], each lane owns 2 dims. K/V/gate loaded once per source
// (coalesced); only dst Q (bf16, 768B/edge) gathered randomly. Writes are fire-and-forget atomics.
__global__ __launch_bounds__(256) void agg_kernel(
    const u16* __restrict__ Qb,       // [n][t][64] bf16, prescaled QPRE
    const u16* __restrict__ Kb,       // [n][t][64] bf16
    const u16* __restrict__ Vb,
    const float* __restrict__ gate,   // [n][t]  log2(S+eps)
    const float* __restrict__ kpe,    // [9][64]
    const float* __restrict__ bias,   // [9]  -log2(1+dt)
    const int* __restrict__ row_ptr,
    const int* __restrict__ edge_list,
    float* __restrict__ nu,           // [t][n][64] f32 accum
    float* __restrict__ den) {        // [t][n][4]  f32 accum
    int lane = threadIdx.x & 63, w = threadIdx.x >> 6;
    int s = blockIdx.x * 4 + w;
    if (s >= N_NODES) return;
    int half = lane >> 5;
    int l32 = lane & 31;
    int doff = ((l32 >> 3) << 4) + ((l32 & 7) << 1);   // h*16 + 2*p
    int h = l32 >> 3;

    int e0 = row_ptr[s], e1 = row_ptr[s + 1];
    if (e0 >= e1) return;                              // no out-edges: contributes nothing

    // per-source data (shared by both halves; lanes 32-63 dup-load same addrs — coalesced)
    float k0[T_DIM], k1[T_DIM], v0[T_DIM], v1[T_DIM], g[T_DIM], kp0[T_DIM], kp1[T_DIM], bi[T_DIM];
    #pragma unroll
    for (int t = 0; t < T_DIM; ++t) {
        u32 ku = *(const u32*)(Kb + ((size_t)s * T_DIM + t) * 64 + doff);
        u32 vu = *(const u32*)(Vb + ((size_t)s * T_DIM + t) * 64 + doff);
        k0[t] = __int_as_float((int)(ku << 16));
        k1[t] = __int_as_float((int)(ku & 0xffff0000u));
        v0[t] = __int_as_float((int)(vu << 16));
        v1[t] = __int_as_float((int)(vu & 0xffff0000u));
        g[t] = gate[s * T_DIM + t];
        float2 kp = *(const float2*)(kpe + t * 64 + doff);
        kp0[t] = kp.x; kp1[t] = kp.y;
        bi[t] = bias[t];
    }

    int nq = (e1 - e0 + 1) >> 1;
    int d; bool valid; u32 qu[T_DIM];
    {   // prologue: this half's first edge
        int i = e0 + half;
        valid = i < e1;
        d = edge_list[min(i, e1 - 1)];
        #pragma unroll
        for (int t = 0; t < T_DIM; ++t)
            qu[t] = *(const u32*)(Qb + ((size_t)d * T_DIM + t) * 64 + doff);
    }

    for (int p = 0; p < nq; ++p) {
        // prefetch next pair's dst + Q (clamped; overlaps compute)
        int d2; bool valid2; u32 qu2[T_DIM];
        {
            int i = e0 + (p + 1) * 2 + half;
            valid2 = i < e1;
            d2 = edge_list[min(i, e1 - 1)];
            #pragma unroll
            for (int t = 0; t < T_DIM; ++t)
                qu2[t] = *(const u32*)(Qb + ((size_t)d2 * T_DIM + t) * 64 + doff);
        }
        // compute current edge: score = q.(K[tp]+kpe[dt]) + bias[dt] + gate[tp]  (exp2 domain)
        float q0[T_DIM], q1[T_DIM];
        #pragma unroll
        for (int t = 0; t < T_DIM; ++t) {
            q0[t] = __int_as_float((int)(qu[t] << 16));
            q1[t] = __int_as_float((int)(qu[t] & 0xffff0000u));
        }
        float na0[T_DIM] = {0,0,0,0,0,0};
        float na1[T_DIM] = {0,0,0,0,0,0};
        float da[T_DIM]  = {0,0,0,0,0,0};
        #pragma unroll
        for (int tp = 0; tp < T_DIM; ++tp) {
            #pragma unroll
            for (int t = tp; t < T_DIM; ++t) {
                int dt = t - tp;
                float p0 = k0[tp] + kp0[dt];
                float p1 = k1[tp] + kp1[dt];
                float part = fmaf(q1[t], p1, q0[t] * p0);
                float wt = fast_exp2(red8(part) + bi[dt] + g[tp]);
                da[t] += wt;
                na0[t] = fmaf(wt, v0[tp], na0[t]);
                na1[t] = fmaf(wt, v1[tp], na1[t]);
            }
        }
        if (valid) {
            #pragma unroll
            for (int t = 0; t < T_DIM; ++t) {
                float* np = nu + ((size_t)t * N_NODES + d) * 64 + doff;
                atomicAdd(np, na0[t]);
                atomicAdd(np + 1, na1[t]);
                if ((l32 & 7) == 0)
                    atomicAdd(den + ((size_t)t * N_NODES + d) * 4 + h, da[t]);
            }
        }
        d = d2; valid = valid2;
        #pragma unroll
        for (int t = 0; t < T_DIM; ++t) qu[t] = qu2[t];
    }
}

// ---------------- normalize: out = nu / max(den, 1e-12) ----------------
__global__ __launch_bounds__(256) void norm_kernel(const float* __restrict__ nu,
                                                   const float* __restrict__ den,
                                                   float* __restrict__ out) {
    int i = blockIdx.x * 256 + threadIdx.x;          // one float4 per thread
    if (i >= TOTAL_ROWS * 16) return;
    int base = i * 4;
    int row = base >> 6;                             // t*N + n
    int h = (base >> 4) & 3;
    float r = 1.0f / fmaxf(den[row * 4 + h], 1e-12f);
    float4 v = ((const float4*)nu)[i];
    ((float4*)out)[i] = make_float4(v.x * r, v.y * r, v.z * r, v.w * r);
}

extern "C" void kernel_launch(void* const* d_in, const int* in_sizes, int n_in,
                              void* d_out, int out_size, void* d_ws, size_t ws_size,
                              hipStream_t stream) {
    const float* H  = (const float*)d_in[0];
    const float* S  = (const float*)d_in[1];
    const float* Wq = (const float*)d_in[2];
    const float* Wk = (const float*)d_in[3];
    const float* Wv = (const float*)d_in[4];
    const int* edge = (const int*)d_in[5];
    int E = in_sizes[5] / 2;
    const int* esrc = edge;
    const int* edst = edge + E;
    float* out = (float*)d_out;

    char* ws = (char*)d_ws;
    size_t off = 0;
    auto alloc = [&](size_t b) { char* p = ws + off; off += (b + 255) & ~(size_t)255; return (void*)p; };
    u16*   Qb        = (u16*)  alloc((size_t)TOTAL_ROWS * 64 * 2);   // 7.68 MB
    u16*   Kb        = (u16*)  alloc((size_t)TOTAL_ROWS * 64 * 2);   // 7.68 MB
    u16*   Vb        = (u16*)  alloc((size_t)TOTAL_ROWS * 64 * 2);   // 7.68 MB
    float* nu        = (float*)alloc((size_t)TOTAL_ROWS * 64 * 4);   // 15.36 MB
    float* den       = (float*)alloc((size_t)TOTAL_ROWS * 4 * 4);    // 0.96 MB
    float* gate      = (float*)alloc((size_t)TOTAL_ROWS * 4);        // 240 KB
    float* kpe       = (float*)alloc(9 * 64 * 4);
    float* bias      = (float*)alloc(9 * 4);
    int*   counts    = (int*)  alloc((size_t)N_NODES * 4);
    int*   cursor    = (int*)  alloc((size_t)N_NODES * 4);
    int*   row_ptr   = (int*)  alloc((size_t)(N_NODES + 1) * 4);
    int*   edge_list = (int*)  alloc((size_t)E * 4);

    zero_kernel<<<1024, 256, 0, stream>>>(counts, nu, den, Wk, kpe, bias);
    int proj_blocks = (TOTAL_ROWS / 32 + 3) / 4;   // 469
    proj_kernel<<<proj_blocks, 256, 0, stream>>>(H, S, Wq, Wk, Wv, esrc, E, counts, Qb, Kb, Vb, gate);
    scan_kernel<<<1, SCAN_THREADS, 0, stream>>>(counts, row_ptr, cursor);
    scatter_kernel<<<(E + 255) / 256, 256, 0, stream>>>(esrc, edst, cursor, edge_list, E);
    agg_kernel<<<(N_NODES + 3) / 4, 256, 0, stream>>>(Qb, Kb, Vb, gate, kpe, bias, row_ptr, edge_list, nu, den);
    norm_kernel<<<(TOTAL_ROWS * 16 + 255) / 256, 256, 0, stream>>>(nu, den, out);
}

// Round 9
// 57.820 us; speedup vs baseline: 5.9647x; 4.4862x over previous
//
#include <hip/hip_runtime.h>
#include <hip/hip_bf16.h>

#define T_DIM 6
#define N_NODES 10000
#define TOTAL_ROWS (T_DIM * N_NODES)   // 60000
#define LOG2E 1.44269504088896340736f
#define QPRE (0.25f * LOG2E)           // dh^-0.5 * log2(e): softmax done in exp2 domain
#define EPS_GATE 1e-6f
#define NEGBIG (-1e30f)
#define CAP 64                         // max in-degree supported (Poisson(5), max ~20; guarded)
#define REC 832                        // record stride in u16: K[6][64] | V[6][64] | gate[6]f32 | pad

typedef unsigned int u32;
typedef unsigned short u16;
typedef __attribute__((ext_vector_type(8))) short bf16x8;
typedef __attribute__((ext_vector_type(4))) float f32x4;

#define MFMA16(a, b, c) __builtin_amdgcn_mfma_f32_16x16x32_bf16(a, b, c, 0, 0, 0)

__device__ __forceinline__ float fast_exp2(float x) {
#if __has_builtin(__builtin_amdgcn_exp2f)
    return __builtin_amdgcn_exp2f(x);
#else
    return exp2f(x);
#endif
}

// DPP butterfly add within 4-lane quads.
template <int CTRL>
__device__ __forceinline__ float dpp_add(float x) {
    int v = __builtin_amdgcn_update_dpp(0, __float_as_int(x), CTRL, 0xf, 0xf, true);
    return x + __int_as_float(v);
}
__device__ __forceinline__ float red4(float x) {
    x = dpp_add<0xB1>(x);   // quad_perm {1,0,3,2} : lane ^ 1
    x = dpp_add<0x4E>(x);   // quad_perm {2,3,0,1} : lane ^ 2
    return x;               // all 4 lanes of the quad hold the sum
}

__device__ __forceinline__ float bf2f(u16 u) {
    union { unsigned int i; float f; } c;
    c.i = ((unsigned int)u) << 16;
    return c.f;
}

__device__ __forceinline__ u16 f2bf(float f) {
    union { float f; unsigned int i; } c; c.f = f;
    unsigned int i = c.i;
    unsigned int lsb = (i >> 16) & 1u;
    i += 0x7FFFu + lsb;          // round-to-nearest-even (finite data only)
    return (u16)(i >> 16);
}

// ------- K1: cursor zero + gate-into-record + kpe/bias tables + MFMA QKV projection -------
// Q (f32, prescaled QPRE) -> out [t][n][64].  K/V (bf16) + gate (f32) -> KVG records [n].
__global__ __launch_bounds__(256) void proj_kernel(
    const float* __restrict__ H,
    const float* __restrict__ S,
    const float* __restrict__ Wq, const float* __restrict__ Wk,
    const float* __restrict__ Wv,
    int* __restrict__ cursor,
    float* __restrict__ Qs, u16* __restrict__ KVG,
    float* __restrict__ kpe, float* __restrict__ bias) {
    int tid = threadIdx.x;
    int gtid = blockIdx.x * 256 + tid;
    // ---- prep: zero cursor; gate rows (24B contiguous per node) ----
    if (gtid < N_NODES) {
        cursor[gtid] = 0;
        float* gp = (float*)(KVG + (size_t)gtid * REC + 768);
        #pragma unroll
        for (int t = 0; t < T_DIM; ++t)
            gp[t] = log2f(S[t * N_NODES + gtid] + EPS_GATE);
    }
    if (blockIdx.x == 0 && tid < 64) {
        int c = tid;
        for (int dt = 0; dt < 9; ++dt) {
            float fdt = (float)dt;
            float pe[8];
            pe[0] = expf(-fdt * 0.25f);    // tau=4
            pe[1] = expf(-fdt * 0.0625f);  // tau=16
            pe[2] = sinf(fdt * 1.0f);
            pe[3] = sinf(fdt * 0.5f);
            pe[4] = sinf(fdt * 0.25f);
            pe[5] = cosf(fdt * 1.0f);
            pe[6] = cosf(fdt * 0.5f);
            pe[7] = cosf(fdt * 0.25f);
            float acc = 0.f;
            #pragma unroll
            for (int j = 0; j < 8; ++j) acc += pe[j] * Wk[c * 72 + 64 + j];
            kpe[dt * 64 + c] = acc;
            if (c == 0) bias[dt] = -log2f(1.0f + fdt);
        }
    }

    // ---- weight staging ----
    __shared__ short whi[192][72];   // stride 72 shorts = 144B -> 2-way banks (free)
    __shared__ short wlo[192][72];
    for (int i = tid; i < 192 * 64; i += 256) {
        int col = i >> 6, k = i & 63;
        float w;
        if (col < 64)       w = Wq[col * 64 + k];
        else if (col < 128) w = Wk[(col - 64) * 72 + k];   // first 64 input dims of W_k
        else                w = Wv[(col - 128) * 64 + k];
        u16 hb = f2bf(w);
        whi[col][k] = (short)hb;
        wlo[col][k] = (short)f2bf(w - bf2f(hb));
    }
    __syncthreads();

    int lane = tid & 63, wid = tid >> 6;
    int r0 = (blockIdx.x * 4 + wid) * 32;          // 32 rows per wave (60000 = 32*1875)
    if (r0 >= TOTAL_ROWS) return;

    int mrow = lane & 15;
    int kgrp = lane >> 4;                          // 0..3

    // A fragments: [mtile][kstep], hi+lo split (f32 accuracy: h*w ~= hi*whi + hi*wlo + lo*whi)
    bf16x8 ahi[2][2], alo[2][2];
    #pragma unroll
    for (int mt = 0; mt < 2; ++mt) {
        #pragma unroll
        for (int ks = 0; ks < 2; ++ks) {
            const float* hp = H + (size_t)(r0 + mt * 16 + mrow) * 64 + ks * 32 + kgrp * 8;
            float4 hA = *(const float4*)hp;
            float4 hB = *(const float4*)(hp + 4);
            float tmp[8] = {hA.x, hA.y, hA.z, hA.w, hB.x, hB.y, hB.z, hB.w};
            #pragma unroll
            for (int b = 0; b < 8; ++b) {
                u16 hb = f2bf(tmp[b]);
                ahi[mt][ks][b] = (short)hb;
                alo[mt][ks][b] = (short)f2bf(tmp[b] - bf2f(hb));
            }
        }
    }

    #pragma unroll
    for (int nt = 0; nt < 12; ++nt) {
        f32x4 acc0 = {0.f, 0.f, 0.f, 0.f};
        f32x4 acc1 = {0.f, 0.f, 0.f, 0.f};
        #pragma unroll
        for (int ks = 0; ks < 2; ++ks) {
            bf16x8 bh = *(const bf16x8*)&whi[nt * 16 + mrow][ks * 32 + kgrp * 8];
            bf16x8 bl = *(const bf16x8*)&wlo[nt * 16 + mrow][ks * 32 + kgrp * 8];
            acc0 = MFMA16(ahi[0][ks], bh, acc0);
            acc0 = MFMA16(ahi[0][ks], bl, acc0);
            acc0 = MFMA16(alo[0][ks], bh, acc0);
            acc1 = MFMA16(ahi[1][ks], bh, acc1);
            acc1 = MFMA16(ahi[1][ks], bl, acc1);
            acc1 = MFMA16(alo[1][ks], bh, acc1);
        }
        // epilogue: C col = lane&15, row = (lane>>4)*4 + j   [m89-verified]
        #pragma unroll
        for (int mt = 0; mt < 2; ++mt) {
            f32x4 acc = mt ? acc1 : acc0;
            int mbase = r0 + mt * 16 + kgrp * 4;
            #pragma unroll
            for (int j = 0; j < 4; ++j) {
                int gr = mbase + j;
                float v = acc[j];
                int t = gr / N_NODES, n = gr - t * N_NODES;
                int col = (nt & 3) * 16 + mrow;
                if (nt < 4)      Qs[(size_t)gr * 64 + col] = v * QPRE;
                else if (nt < 8) KVG[(size_t)n * REC + t * 64 + col] = f2bf(v);
                else             KVG[(size_t)n * REC + 384 + t * 64 + col] = f2bf(v);
            }
        }
    }
}

// ------- K2: scatter edges into fixed-capacity per-dst slots (atomic = hist + rank) -------
__global__ void scatter_kernel(const int* __restrict__ esrc, const int* __restrict__ edst,
                               int* __restrict__ cursor, int* __restrict__ slots, int E) {
    int e = blockIdx.x * blockDim.x + threadIdx.x;
    if (e < E) {
        int d = edst[e];
        int pos = atomicAdd(&cursor[d], 1);
        if (pos < CAP) slots[d * CAP + pos] = esrc[e];
    }
}

// ------- K3: aggregation: one wave per node, 4 edges/iter, slots in-register via shfl -------
// lane = e4*16 + (h*4 + dg) : edge-group(4) x [head(4) x dim-quad(4)]; lane owns 4 dims.
__global__ __launch_bounds__(256) void agg_kernel(
    const float* __restrict__ Qs,     // [t][n][64] f32, prescaled (aliases out)
    const u16* __restrict__ KVG,      // per-node records
    const float* __restrict__ kpe,    // [9][64]
    const float* __restrict__ bias,   // [9]  -log2(1+dt)
    const int* __restrict__ deg_arr,  // cursor = in-degree
    const int* __restrict__ slots,    // [n][CAP]
    float* __restrict__ out) {
    int lane = threadIdx.x & 63, w = threadIdx.x >> 6;
    int n = blockIdx.x * 4 + w;
    int e4 = lane >> 4;                      // which of 4 edges
    int doff = (lane & 15) << 2;             // dim offset, 4 dims per lane

    int deg = deg_arr[n];
    if (deg <= 0) {                          // zero-degree: output 0 (matches ref clip)
        if (e4 == 0) {
            #pragma unroll
            for (int t = 0; t < T_DIM; ++t)
                *(float4*)(out + ((size_t)t * N_NODES + n) * 64 + doff) =
                    make_float4(0.f, 0.f, 0.f, 0.f);
        }
        return;
    }
    deg = min(deg, CAP);
    int slotv = slots[n * CAP + lane];       // ALL edge indices in one coalesced load

    float4 q[T_DIM];
    #pragma unroll
    for (int t = 0; t < T_DIM; ++t)
        q[t] = *(const float4*)(Qs + ((size_t)t * N_NODES + n) * 64 + doff);

    // cc[tri(t,dt)] = dot16(q[t], K_pe[dt]) + bias[dt]  (uniform within each quad)
    float cc[21];
    #pragma unroll
    for (int dt = 0; dt < T_DIM; ++dt) {
        float4 kp = *(const float4*)(kpe + dt * 64 + doff);
        float b = bias[dt];
        #pragma unroll
        for (int t = dt; t < T_DIM; ++t) {
            float part = q[t].x * kp.x;
            part = fmaf(q[t].y, kp.y, part);
            part = fmaf(q[t].z, kp.z, part);
            part = fmaf(q[t].w, kp.w, part);
            cc[t * (t + 1) / 2 + dt] = red4(part) + b;
        }
    }

    float den[T_DIM] = {0,0,0,0,0,0};
    float4 nu[T_DIM];
    #pragma unroll
    for (int t = 0; t < T_DIM; ++t) nu[t] = make_float4(0.f, 0.f, 0.f, 0.f);

    int ng = (deg + 3) >> 2;
    uint2 ku[T_DIM], vu[T_DIM];
    float gg[T_DIM];

    // prologue: group 0 (invalid edges -> gate = -1e30 -> weight 0)
    {
        int eidx = e4;
        int s = __shfl(slotv, min(eidx, deg - 1));
        const u16* base = KVG + (size_t)s * REC;
        #pragma unroll
        for (int t = 0; t < T_DIM; ++t) {
            ku[t] = *(const uint2*)(base + t * 64 + doff);
            vu[t] = *(const uint2*)(base + 384 + t * 64 + doff);
        }
        const float* gp = (const float*)(base + 768);
        bool val = eidx < deg;
        #pragma unroll
        for (int t = 0; t < T_DIM; ++t) gg[t] = val ? gp[t] : NEGBIG;
    }

    for (int g = 0; g < ng; ++g) {
        // ---- prefetch group g+1 (clamped; index via register shfl, no memory hop) ----
        uint2 ku2[T_DIM], vu2[T_DIM];
        float gg2[T_DIM];
        {
            int eidx = (g + 1) * 4 + e4;
            int s = __shfl(slotv, min(eidx, deg - 1));
            const u16* base = KVG + (size_t)s * REC;
            #pragma unroll
            for (int t = 0; t < T_DIM; ++t) {
                ku2[t] = *(const uint2*)(base + t * 64 + doff);
                vu2[t] = *(const uint2*)(base + 384 + t * 64 + doff);
            }
            const float* gp = (const float*)(base + 768);
            bool val = eidx < deg;
            #pragma unroll
            for (int t = 0; t < T_DIM; ++t) gg2[t] = val ? gp[t] : NEGBIG;
        }
        // ---- compute current group: tp-outer keeps one K/V row unpacked at a time ----
        #pragma unroll
        for (int tp = 0; tp < T_DIM; ++tp) {
            float k0 = bf2f((u16)(ku[tp].x & 0xffff));
            float k1 = bf2f((u16)(ku[tp].x >> 16));
            float k2 = bf2f((u16)(ku[tp].y & 0xffff));
            float k3 = bf2f((u16)(ku[tp].y >> 16));
            float v0 = bf2f((u16)(vu[tp].x & 0xffff));
            float v1 = bf2f((u16)(vu[tp].x >> 16));
            float v2 = bf2f((u16)(vu[tp].y & 0xffff));
            float v3 = bf2f((u16)(vu[tp].y >> 16));
            float gv = gg[tp];
            #pragma unroll
            for (int t = tp; t < T_DIM; ++t) {
                int dt = t - tp;
                float part = q[t].x * k0;
                part = fmaf(q[t].y, k1, part);
                part = fmaf(q[t].z, k2, part);
                part = fmaf(q[t].w, k3, part);
                float wt = fast_exp2(red4(part) + cc[t * (t + 1) / 2 + dt] + gv);
                den[t] += wt;
                nu[t].x = fmaf(wt, v0, nu[t].x);
                nu[t].y = fmaf(wt, v1, nu[t].y);
                nu[t].z = fmaf(wt, v2, nu[t].z);
                nu[t].w = fmaf(wt, v3, nu[t].w);
            }
        }
        #pragma unroll
        for (int t = 0; t < T_DIM; ++t) { ku[t] = ku2[t]; vu[t] = vu2[t]; gg[t] = gg2[t]; }
    }

    // combine the four edge-groups (once per node), then store
    #pragma unroll
    for (int t = 0; t < T_DIM; ++t) {
        den[t] += __shfl_xor(den[t], 16);  den[t] += __shfl_xor(den[t], 32);
        nu[t].x += __shfl_xor(nu[t].x, 16); nu[t].x += __shfl_xor(nu[t].x, 32);
        nu[t].y += __shfl_xor(nu[t].y, 16); nu[t].y += __shfl_xor(nu[t].y, 32);
        nu[t].z += __shfl_xor(nu[t].z, 16); nu[t].z += __shfl_xor(nu[t].z, 32);
        nu[t].w += __shfl_xor(nu[t].w, 16); nu[t].w += __shfl_xor(nu[t].w, 32);
    }
    if (e4 == 0) {
        #pragma unroll
        for (int t = 0; t < T_DIM; ++t) {
            float r = 1.0f / fmaxf(den[t], 1e-12f);
            *(float4*)(out + ((size_t)t * N_NODES + n) * 64 + doff) =
                make_float4(nu[t].x * r, nu[t].y * r, nu[t].z * r, nu[t].w * r);
        }
    }
}

extern "C" void kernel_launch(void* const* d_in, const int* in_sizes, int n_in,
                              void* d_out, int out_size, void* d_ws, size_t ws_size,
                              hipStream_t stream) {
    const float* H  = (const float*)d_in[0];
    const float* S  = (const float*)d_in[1];
    const float* Wq = (const float*)d_in[2];
    const float* Wk = (const float*)d_in[3];
    const float* Wv = (const float*)d_in[4];
    const int* edge = (const int*)d_in[5];
    int E = in_sizes[5] / 2;
    const int* esrc = edge;
    const int* edst = edge + E;
    float* out = (float*)d_out;

    char* ws = (char*)d_ws;
    size_t off = 0;
    auto alloc = [&](size_t b) { char* p = ws + off; off += (b + 255) & ~(size_t)255; return (void*)p; };
    u16*   KVG     = (u16*)  alloc((size_t)N_NODES * REC * 2);    // 16.64 MB records
    int*   cursor  = (int*)  alloc((size_t)N_NODES * 4);          // degree + scatter rank
    int*   slots   = (int*)  alloc((size_t)N_NODES * CAP * 4);    // 2.56 MB edge lists
    float* kpe     = (float*)alloc(9 * 64 * 4);
    float* bias    = (float*)alloc(9 * 4);

    int proj_blocks = (TOTAL_ROWS / 32 + 3) / 4;   // 469
    proj_kernel<<<proj_blocks, 256, 0, stream>>>(H, S, Wq, Wk, Wv, cursor, out, KVG, kpe, bias);
    scatter_kernel<<<(E + 255) / 256, 256, 0, stream>>>(esrc, edst, cursor, slots, E);
    agg_kernel<<<(N_NODES + 3) / 4, 256, 0, stream>>>(out, KVG, kpe, bias, cursor, slots, out);
}

// Round 10
// 56.393 us; speedup vs baseline: 6.1156x; 1.0253x over previous
//
#include <hip/hip_runtime.h>
#include <hip/hip_bf16.h>

#define T_DIM 6
#define N_NODES 10000
#define TOTAL_ROWS (T_DIM * N_NODES)   // 60000
#define LOG2E 1.44269504088896340736f
#define QPRE (0.25f * LOG2E)           // dh^-0.5 * log2(e): softmax done in exp2 domain
#define EPS_GATE 1e-6f
#define NEGBIG (-1e30f)
#define CAP 64                         // max in-degree supported (Poisson(5); guarded)
// record stride in u16: KV-interleaved [t][64][2] = 768 u16 | gate[6] f32 (=12 u16) | pad
#define REC 832                        // 1664 B, 64B-aligned

typedef unsigned int u32;
typedef unsigned short u16;
typedef __attribute__((ext_vector_type(8))) short bf16x8;
typedef __attribute__((ext_vector_type(4))) float f32x4;

#define MFMA16(a, b, c) __builtin_amdgcn_mfma_f32_16x16x32_bf16(a, b, c, 0, 0, 0)

__device__ __forceinline__ float fast_exp2(float x) {
#if __has_builtin(__builtin_amdgcn_exp2f)
    return __builtin_amdgcn_exp2f(x);
#else
    return exp2f(x);
#endif
}

// DPP butterfly add within 4-lane quads.
template <int CTRL>
__device__ __forceinline__ float dpp_add(float x) {
    int v = __builtin_amdgcn_update_dpp(0, __float_as_int(x), CTRL, 0xf, 0xf, true);
    return x + __int_as_float(v);
}
__device__ __forceinline__ float red4(float x) {
    x = dpp_add<0xB1>(x);   // quad_perm {1,0,3,2} : lane ^ 1
    x = dpp_add<0x4E>(x);   // quad_perm {2,3,0,1} : lane ^ 2
    return x;               // all 4 lanes of the quad hold the sum
}

__device__ __forceinline__ float bf2f(u16 u) {
    union { unsigned int i; float f; } c;
    c.i = ((unsigned int)u) << 16;
    return c.f;
}

__device__ __forceinline__ u16 f2bf(float f) {
    union { float f; unsigned int i; } c; c.f = f;
    unsigned int i = c.i;
    unsigned int lsb = (i >> 16) & 1u;
    i += 0x7FFFu + lsb;          // round-to-nearest-even (finite data only)
    return (u16)(i >> 16);
}

// ------- K1: cursor zero + gate-into-record + kpe/bias tables + MFMA QKV projection -------
// Q (bf16, prescaled QPRE) -> Qb [t][n][64].  K/V (bf16, dim-interleaved) + gate (f32) -> KVG [n].
__global__ __launch_bounds__(256) void proj_kernel(
    const float* __restrict__ H,
    const float* __restrict__ S,
    const float* __restrict__ Wq, const float* __restrict__ Wk,
    const float* __restrict__ Wv,
    int* __restrict__ cursor,
    u16* __restrict__ Qb, u16* __restrict__ KVG,
    float* __restrict__ kpe, float* __restrict__ bias) {
    int tid = threadIdx.x;
    int gtid = blockIdx.x * 256 + tid;
    // ---- prep: zero cursor; gate rows (24B contiguous per record) ----
    if (gtid < N_NODES) {
        cursor[gtid] = 0;
        float* gp = (float*)(KVG + (size_t)gtid * REC + 768);
        #pragma unroll
        for (int t = 0; t < T_DIM; ++t)
            gp[t] = log2f(S[t * N_NODES + gtid] + EPS_GATE);
    }
    if (blockIdx.x == 0 && tid < 64) {
        int c = tid;
        for (int dt = 0; dt < 9; ++dt) {
            float fdt = (float)dt;
            float pe[8];
            pe[0] = expf(-fdt * 0.25f);    // tau=4
            pe[1] = expf(-fdt * 0.0625f);  // tau=16
            pe[2] = sinf(fdt * 1.0f);
            pe[3] = sinf(fdt * 0.5f);
            pe[4] = sinf(fdt * 0.25f);
            pe[5] = cosf(fdt * 1.0f);
            pe[6] = cosf(fdt * 0.5f);
            pe[7] = cosf(fdt * 0.25f);
            float acc = 0.f;
            #pragma unroll
            for (int j = 0; j < 8; ++j) acc += pe[j] * Wk[c * 72 + 64 + j];
            kpe[dt * 64 + c] = acc;
            if (c == 0) bias[dt] = -log2f(1.0f + fdt);
        }
    }

    // ---- weight staging ----
    __shared__ short whi[192][72];   // stride 72 shorts = 144B -> 2-way banks (free)
    __shared__ short wlo[192][72];
    for (int i = tid; i < 192 * 64; i += 256) {
        int col = i >> 6, k = i & 63;
        float w;
        if (col < 64)       w = Wq[col * 64 + k];
        else if (col < 128) w = Wk[(col - 64) * 72 + k];   // first 64 input dims of W_k
        else                w = Wv[(col - 128) * 64 + k];
        u16 hb = f2bf(w);
        whi[col][k] = (short)hb;
        wlo[col][k] = (short)f2bf(w - bf2f(hb));
    }
    __syncthreads();

    int lane = tid & 63, wid = tid >> 6;
    int r0 = (blockIdx.x * 4 + wid) * 32;          // 32 rows per wave (60000 = 32*1875)
    if (r0 >= TOTAL_ROWS) return;

    int mrow = lane & 15;
    int kgrp = lane >> 4;                          // 0..3

    // A fragments: [mtile][kstep], hi+lo split (f32 accuracy: h*w ~= hi*whi + hi*wlo + lo*whi)
    bf16x8 ahi[2][2], alo[2][2];
    #pragma unroll
    for (int mt = 0; mt < 2; ++mt) {
        #pragma unroll
        for (int ks = 0; ks < 2; ++ks) {
            const float* hp = H + (size_t)(r0 + mt * 16 + mrow) * 64 + ks * 32 + kgrp * 8;
            float4 hA = *(const float4*)hp;
            float4 hB = *(const float4*)(hp + 4);
            float tmp[8] = {hA.x, hA.y, hA.z, hA.w, hB.x, hB.y, hB.z, hB.w};
            #pragma unroll
            for (int b = 0; b < 8; ++b) {
                u16 hb = f2bf(tmp[b]);
                ahi[mt][ks][b] = (short)hb;
                alo[mt][ks][b] = (short)f2bf(tmp[b] - bf2f(hb));
            }
        }
    }

    #pragma unroll
    for (int nt = 0; nt < 12; ++nt) {
        f32x4 acc0 = {0.f, 0.f, 0.f, 0.f};
        f32x4 acc1 = {0.f, 0.f, 0.f, 0.f};
        #pragma unroll
        for (int ks = 0; ks < 2; ++ks) {
            bf16x8 bh = *(const bf16x8*)&whi[nt * 16 + mrow][ks * 32 + kgrp * 8];
            bf16x8 bl = *(const bf16x8*)&wlo[nt * 16 + mrow][ks * 32 + kgrp * 8];
            acc0 = MFMA16(ahi[0][ks], bh, acc0);
            acc0 = MFMA16(ahi[0][ks], bl, acc0);
            acc0 = MFMA16(alo[0][ks], bh, acc0);
            acc1 = MFMA16(ahi[1][ks], bh, acc1);
            acc1 = MFMA16(ahi[1][ks], bl, acc1);
            acc1 = MFMA16(alo[1][ks], bh, acc1);
        }
        // epilogue: C col = lane&15, row = (lane>>4)*4 + j   [m89-verified]
        #pragma unroll
        for (int mt = 0; mt < 2; ++mt) {
            f32x4 acc = mt ? acc1 : acc0;
            int mbase = r0 + mt * 16 + kgrp * 4;
            #pragma unroll
            for (int j = 0; j < 4; ++j) {
                int gr = mbase + j;
                float v = acc[j];
                int t = gr / N_NODES, n = gr - t * N_NODES;
                int col = (nt & 3) * 16 + mrow;
                if (nt < 4)      Qb[(size_t)gr * 64 + col] = f2bf(v * QPRE);
                else if (nt < 8) KVG[(size_t)n * REC + t * 128 + col * 2] = f2bf(v);
                else             KVG[(size_t)n * REC + t * 128 + col * 2 + 1] = f2bf(v);
            }
        }
    }
}

// ------- K2: scatter edges into fixed-capacity per-dst slots (atomic = hist + rank) -------
__global__ void scatter_kernel(const int* __restrict__ esrc, const int* __restrict__ edst,
                               int* __restrict__ cursor, int* __restrict__ slots, int E) {
    int e = blockIdx.x * blockDim.x + threadIdx.x;
    if (e < E) {
        int d = edst[e];
        int pos = atomicAdd(&cursor[d], 1);
        if (pos < CAP) slots[d * CAP + pos] = esrc[e];
    }
}

// ------- K3: aggregation: one wave per node, 4 edges/iter, KV-interleaved dwordx4 gather -------
// lane = e4*16 + (h*4 + dg) : edge-group(4) x [head(4) x dim-quad(4)]; lane owns 4 dims.
__global__ __launch_bounds__(128) void agg_kernel(
    const u16* __restrict__ Qb,       // [t][n][64] bf16, prescaled QPRE
    const u16* __restrict__ KVG,      // per-node records, KV interleaved
    const float* __restrict__ kpe,    // [9][64]
    const float* __restrict__ bias,   // [9]  -log2(1+dt)
    const int* __restrict__ deg_arr,  // cursor = in-degree
    const int* __restrict__ slots,    // [n][CAP]
    float* __restrict__ out) {
    int lane = threadIdx.x & 63, w = threadIdx.x >> 6;
    int n = blockIdx.x * 2 + w;
    int e4 = lane >> 4;                      // which of 4 edges
    int doff = (lane & 15) << 2;             // dim offset, 4 dims per lane

    // issue independent loads up front (deg is the only branch dependency)
    int deg = deg_arr[n];
    int slotv = slots[n * CAP + lane];       // ALL edge indices in one coalesced load
    uint2 qraw[T_DIM];
    #pragma unroll
    for (int t = 0; t < T_DIM; ++t)
        qraw[t] = *(const uint2*)(Qb + ((size_t)t * N_NODES + n) * 64 + doff);

    if (deg <= 0) {                          // zero-degree: output 0 (matches ref clip)
        if (e4 == 0) {
            #pragma unroll
            for (int t = 0; t < T_DIM; ++t)
                *(float4*)(out + ((size_t)t * N_NODES + n) * 64 + doff) =
                    make_float4(0.f, 0.f, 0.f, 0.f);
        }
        return;
    }
    deg = min(deg, CAP);
    int ng = (deg + 3) >> 2;

    uint4 kvA[T_DIM], kvB[T_DIM];
    float ggA[T_DIM], ggB[T_DIM];

#define LOADG(BASE, KV, GG) {                                                   \
        int eidx = (BASE) + e4;                                                 \
        int sidx = __shfl(slotv, min(eidx, deg - 1));                           \
        const u16* bp = KVG + (size_t)sidx * REC;                               \
        _Pragma("unroll")                                                       \
        for (int t = 0; t < T_DIM; ++t)                                         \
            KV[t] = *(const uint4*)(bp + t * 128 + doff * 2);                   \
        const float* gp = (const float*)(bp + 768);                             \
        float4 gA = *(const float4*)gp;                                         \
        float2 gB = *(const float2*)(gp + 4);                                   \
        bool val = eidx < deg;                                                  \
        GG[0] = val ? gA.x : NEGBIG; GG[1] = val ? gA.y : NEGBIG;               \
        GG[2] = val ? gA.z : NEGBIG; GG[3] = val ? gA.w : NEGBIG;               \
        GG[4] = val ? gB.x : NEGBIG; GG[5] = val ? gB.y : NEGBIG;               \
    }

    // preload groups 0 and 1 (both in flight before any compute)
    LOADG(0, kvA, ggA);
    if (ng > 1) LOADG(4, kvB, ggB);

    // unpack q + compute cc while the gathers are in flight
    float4 q[T_DIM];
    #pragma unroll
    for (int t = 0; t < T_DIM; ++t) {
        q[t].x = bf2f((u16)(qraw[t].x & 0xffff));
        q[t].y = bf2f((u16)(qraw[t].x >> 16));
        q[t].z = bf2f((u16)(qraw[t].y & 0xffff));
        q[t].w = bf2f((u16)(qraw[t].y >> 16));
    }
    float cc[21];   // cc[tri(t,dt)] = dot16(q[t], K_pe[dt]) + bias[dt]  (uniform per quad)
    #pragma unroll
    for (int dt = 0; dt < T_DIM; ++dt) {
        float4 kp = *(const float4*)(kpe + dt * 64 + doff);
        float b = bias[dt];
        #pragma unroll
        for (int t = dt; t < T_DIM; ++t) {
            float part = q[t].x * kp.x;
            part = fmaf(q[t].y, kp.y, part);
            part = fmaf(q[t].z, kp.z, part);
            part = fmaf(q[t].w, kp.w, part);
            cc[t * (t + 1) / 2 + dt] = red4(part) + b;
        }
    }

    float den[T_DIM] = {0,0,0,0,0,0};
    float4 nu[T_DIM];
    #pragma unroll
    for (int t = 0; t < T_DIM; ++t) nu[t] = make_float4(0.f, 0.f, 0.f, 0.f);

    for (int g = 0; ; ++g) {
        // ---- compute current group from A buffers: tp-outer, one KV row unpacked at a time ----
        #pragma unroll
        for (int tp = 0; tp < T_DIM; ++tp) {
            uint4 x = kvA[tp];
            float k0 = bf2f((u16)(x.x & 0xffff)), v0 = bf2f((u16)(x.x >> 16));
            float k1 = bf2f((u16)(x.y & 0xffff)), v1 = bf2f((u16)(x.y >> 16));
            float k2 = bf2f((u16)(x.z & 0xffff)), v2 = bf2f((u16)(x.z >> 16));
            float k3 = bf2f((u16)(x.w & 0xffff)), v3 = bf2f((u16)(x.w >> 16));
            float gv = ggA[tp];
            #pragma unroll
            for (int t = tp; t < T_DIM; ++t) {
                int dt = t - tp;
                float part = q[t].x * k0;
                part = fmaf(q[t].y, k1, part);
                part = fmaf(q[t].z, k2, part);
                part = fmaf(q[t].w, k3, part);
                float wt = fast_exp2(red4(part) + cc[t * (t + 1) / 2 + dt] + gv);
                den[t] += wt;
                nu[t].x = fmaf(wt, v0, nu[t].x);
                nu[t].y = fmaf(wt, v1, nu[t].y);
                nu[t].z = fmaf(wt, v2, nu[t].z);
                nu[t].w = fmaf(wt, v3, nu[t].w);
            }
        }
        if (g + 1 >= ng) break;
        #pragma unroll
        for (int t = 0; t < T_DIM; ++t) { kvA[t] = kvB[t]; ggA[t] = ggB[t]; }
        if (g + 2 < ng) LOADG((g + 2) * 4, kvB, ggB);   // wave-uniform gate: no wasted groups
    }
#undef LOADG

    // combine the four edge-groups (once per node), then store
    #pragma unroll
    for (int t = 0; t < T_DIM; ++t) {
        den[t] += __shfl_xor(den[t], 16);  den[t] += __shfl_xor(den[t], 32);
        nu[t].x += __shfl_xor(nu[t].x, 16); nu[t].x += __shfl_xor(nu[t].x, 32);
        nu[t].y += __shfl_xor(nu[t].y, 16); nu[t].y += __shfl_xor(nu[t].y, 32);
        nu[t].z += __shfl_xor(nu[t].z, 16); nu[t].z += __shfl_xor(nu[t].z, 32);
        nu[t].w += __shfl_xor(nu[t].w, 16); nu[t].w += __shfl_xor(nu[t].w, 32);
    }
    if (e4 == 0) {
        #pragma unroll
        for (int t = 0; t < T_DIM; ++t) {
            float r = 1.0f / fmaxf(den[t], 1e-12f);
            *(float4*)(out + ((size_t)t * N_NODES + n) * 64 + doff) =
                make_float4(nu[t].x * r, nu[t].y * r, nu[t].z * r, nu[t].w * r);
        }
    }
}

extern "C" void kernel_launch(void* const* d_in, const int* in_sizes, int n_in,
                              void* d_out, int out_size, void* d_ws, size_t ws_size,
                              hipStream_t stream) {
    const float* H  = (const float*)d_in[0];
    const float* S  = (const float*)d_in[1];
    const float* Wq = (const float*)d_in[2];
    const float* Wk = (const float*)d_in[3];
    const float* Wv = (const float*)d_in[4];
    const int* edge = (const int*)d_in[5];
    int E = in_sizes[5] / 2;
    const int* esrc = edge;
    const int* edst = edge + E;
    float* out = (float*)d_out;

    char* ws = (char*)d_ws;
    size_t off = 0;
    auto alloc = [&](size_t b) { char* p = ws + off; off += (b + 255) & ~(size_t)255; return (void*)p; };
    u16*   KVG     = (u16*)  alloc((size_t)N_NODES * REC * 2);    // 16.64 MB records
    u16*   Qb      = (u16*)  alloc((size_t)TOTAL_ROWS * 64 * 2);  // 7.68 MB
    int*   cursor  = (int*)  alloc((size_t)N_NODES * 4);          // degree + scatter rank
    int*   slots   = (int*)  alloc((size_t)N_NODES * CAP * 4);    // 2.56 MB edge lists
    float* kpe     = (float*)alloc(9 * 64 * 4);
    float* bias    = (float*)alloc(9 * 4);

    int proj_blocks = (TOTAL_ROWS / 32 + 3) / 4;   // 469
    proj_kernel<<<proj_blocks, 256, 0, stream>>>(H, S, Wq, Wk, Wv, cursor, Qb, KVG, kpe, bias);
    scatter_kernel<<<(E + 255) / 256, 256, 0, stream>>>(esrc, edst, cursor, slots, E);
    agg_kernel<<<(N_NODES + 1) / 2, 128, 0, stream>>>(Qb, KVG, kpe, bias, cursor, slots, out);
}